// Round 8
// baseline (152.084 us; speedup 1.0000x reference)
//
#include <hip/hip_runtime.h>
#include <hip/hip_bf16.h>

#define GATE 512
#define MROWS 256
#define NTOT 120581
#define PHK 32            // K per LDS phase (16 phases)

typedef __attribute__((ext_vector_type(8))) short short8;   // 8 bf16
typedef __attribute__((ext_vector_type(4))) float  f32x4;

struct GemmParams {
    const float* W[10];
    const float* p[10];
    const float* bias[10];
};

__device__ __forceinline__ short bf16bits(float x) {
    __hip_bfloat16 h = __float2bfloat16(x);   // RTNE
    return *reinterpret_cast<short*>(&h);
}

__global__ void emb_to_bf16(const float* __restrict__ emb,
                            unsigned short* __restrict__ o) {
    int i = (blockIdx.x * blockDim.x + threadIdx.x) * 8;
    f32x4 a = *(const f32x4*)(emb + i);
    f32x4 b = *(const f32x4*)(emb + i + 4);
    short8 r;
#pragma unroll
    for (int j = 0; j < 4; ++j) { r[j] = bf16bits(a[j]); r[4 + j] = bf16bits(b[j]); }
    *(short8*)(o + i) = r;
}

// Block: 256 rows x 64 cols (W fetched by exactly one block).
// Waves as 2M x 2N: wave(wm,wn) = rows [wm*128,+128) x cols [wn*32,+32)
//   -> A LDS reads halved vs 1Nx4 (frag reused across 2 nf MFMAs).
// A staged in LDS (lgkm domain) double-buffered at K-phase 32 (32 KB -> 4
// blocks/CU); B streamed from HBM one phase ahead (vmcnt counted, each
// barrier only drains loads issued a full compute-phase earlier).
__global__ __launch_bounds__(256, 4) void gate_gemm(GemmParams P,
                                                    const unsigned short* __restrict__ embw,
                                                    float* __restrict__ out)
{
    constexpr int kStarts[11] = {0, 1728, 1792, 38656, 38720, 75584,
                                 75648, 112512, 112576, 120576, 120581};
    __shared__ unsigned short Atile[2][MROWS * PHK];   // 2 x 16 KB

    const int t    = threadIdx.x;
    const int lane = t & 63;
    const int wave = t >> 6;
    const int wm   = wave >> 1;   // M half
    const int wn   = wave & 1;    // N half
    const int lr   = lane & 15;   // frag col (B/C) / frag row (A)
    const int lg   = lane >> 4;   // k-group / C row-group

    // Per-lane column metadata, 2 N-fragments (cols wn*32 + nf*16 + lr)
    const float* wrow[2];
    float pv[2], bv[2];
    bool  valid[2];
    int   ncol[2];
#pragma unroll
    for (int nf = 0; nf < 2; ++nf) {
        int n = blockIdx.x * 64 + wn * 32 + nf * 16 + lr;
        ncol[nf]  = n;
        valid[nf] = n < NTOT;
        int nc = valid[nf] ? n : NTOT - 1;
        int tt = 0;
#pragma unroll
        for (int i = 1; i < 10; ++i) tt += (nc >= kStarts[i]);
        int r = nc - kStarts[tt];
        wrow[nf] = P.W[tt] + (size_t)r * GATE + lg * 8;
        pv[nf]   = P.p[tt][r];
        bv[nf]   = P.bias[tt][r];
    }

    // ---- A staging: pre-swizzled global source, linear LDS dest.
    // LDS 16B-unit u: row = u>>2, slotw = u&3; holds embw[row][p*32 + (slotw^(row&3))*8 ..+8].
    const int srow0 = t >> 2;                      // + i*64 per load (i*64 ≡ 0 mod 4)
    const int sslot = (t & 3) ^ ((t >> 2) & 3);
    const unsigned short* asrc0 = embw + (size_t)srow0 * GATE + sslot * 8;

    auto stage = [&](int buf, int p) {
#pragma unroll
        for (int i = 0; i < 4; ++i) {
            const unsigned short* src = asrc0 + (size_t)i * 64 * GATE + p * PHK;
            unsigned short* dst = &Atile[buf][(size_t)(i * 256 + t) * 8];
            __builtin_amdgcn_global_load_lds(
                (const __attribute__((address_space(1))) void*)src,
                (__attribute__((address_space(3))) void*)dst, 16, 0, 0);
        }
    };

    // A read: row = wm*128 + mf*16 + lr, k-chunk lg stored at slot lg^(row&3)=lg^(lr&3).
    // Bank-quad = 4*(row&7) + slot' -> rows r,r+8 share a quad = 2-way = free (m136).
    const int axor  = lr & 3;
    const int abase = (wm * 128 + lr) * PHK;   // ushort idx; + mf*16*PHK + slot*8

    f32x4 acc[8][2];
#pragma unroll
    for (int i = 0; i < 8; ++i)
#pragma unroll
        for (int j = 0; j < 2; ++j) acc[i][j] = (f32x4){0.f, 0.f, 0.f, 0.f};

    f32x4 Bc[2][2], Bn[2][2];
    auto loadB = [&](f32x4 (&B)[2][2], int p) {
#pragma unroll
        for (int nf = 0; nf < 2; ++nf) {
            B[nf][0] = *(const f32x4*)(wrow[nf] + p * PHK);
            B[nf][1] = *(const f32x4*)(wrow[nf] + p * PHK + 4);
        }
    };

    // Prologue
    stage(0, 0);
    loadB(Bc, 0);
    __syncthreads();

    int buf = 0;
#pragma unroll
    for (int p = 0; p < 16; ++p) {
        if (p < 15) {
            stage(buf ^ 1, p + 1);   // A for next phase (lands during this compute)
            loadB(Bn, p + 1);        // B for next phase (counted wait, never drained cold)
        }

        short8 bfrag[2];
#pragma unroll
        for (int nf = 0; nf < 2; ++nf)
#pragma unroll
            for (int j = 0; j < 4; ++j) {
                bfrag[nf][j]     = bf16bits(Bc[nf][0][j]);
                bfrag[nf][4 + j] = bf16bits(Bc[nf][1][j]);
            }

#pragma unroll
        for (int mf = 0; mf < 8; ++mf) {
            short8 af = *(const short8*)(&Atile[buf][abase + mf * 16 * PHK + (lg ^ axor) * 8]);
            acc[mf][0] = __builtin_amdgcn_mfma_f32_16x16x32_bf16(af, bfrag[0], acc[mf][0], 0, 0, 0);
            acc[mf][1] = __builtin_amdgcn_mfma_f32_16x16x32_bf16(af, bfrag[1], acc[mf][1], 0, 0, 0);
        }

        if (p < 15) {
#pragma unroll
            for (int nf = 0; nf < 2; ++nf) { Bc[nf][0] = Bn[nf][0]; Bc[nf][1] = Bn[nf][1]; }
            __syncthreads();   // drains stage/loadB issued a full phase ago
            buf ^= 1;
        }
    }

    // Epilogue: sigmoid(x+b)*p. C/D map: col = lane&15, row = (lane>>4)*4 + reg.
    // nf innermost: lane-group writes 2x16 = 128 B contiguous per row; the two
    // wn-waves merge to 256 B/row in L2 (measured-cheap pattern).
#pragma unroll
    for (int mf = 0; mf < 8; ++mf) {
#pragma unroll
        for (int q = 0; q < 4; ++q) {
            const int m = wm * 128 + mf * 16 + lg * 4 + q;
            float* orow = out + (size_t)m * NTOT;
#pragma unroll
            for (int nf = 0; nf < 2; ++nf) {
                if (!valid[nf]) continue;
                float x   = acc[mf][nf][q] + bv[nf];
                float e   = __expf(-x);
                float eta = __builtin_amdgcn_rcpf(1.0f + e);
                orow[ncol[nf]] = eta * pv[nf];
            }
        }
    }
}

extern "C" void kernel_launch(void* const* d_in, const int* in_sizes, int n_in,
                              void* d_out, int out_size, void* d_ws, size_t ws_size,
                              hipStream_t stream) {
    const float* emb = (const float*)d_in[0];
    GemmParams P;
    for (int i = 0; i < 10; ++i) {
        P.p[i]    = (const float*)d_in[1 + 3 * i];
        P.W[i]    = (const float*)d_in[2 + 3 * i];
        P.bias[i] = (const float*)d_in[3 + 3 * i];
    }

    unsigned short* embw = (unsigned short*)d_ws;   // 256 KB, L2-resident
    emb_to_bf16<<<(MROWS * GATE) / (256 * 8), 256, 0, stream>>>(emb, embw);

    int nblocks = (NTOT + 63) / 64;   // 1885
    gate_gemm<<<nblocks, 256, 0, stream>>>(P, embw, (float*)d_out);
}